// Round 1
// baseline (875.749 us; speedup 1.0000x reference)
//
#include <hip/hip_runtime.h>
#include <math.h>

// FICONN photonic NN forward: 5 complex 64x64 unitary layers + nofu nonlinearity + 3-layer MLP.
// fp32 VALU implementation (no fp32 MFMA on CDNA4). Compute-bound: ~52 GFLOP total.

#define NN 64
#define LL 5
#define NMZI 2016            // 64*63/2
#define C_HALF 0.7071067811865476f
#define GAMMA_ 0.05f
#define SENSRESP 0.0008f     // SENS*RESP = 0.001*0.8

// workspace layout (floats)
#define UC_OFF   0                       // UC[l][j][i] as float2 (re,im): U[i][j]*e^{i psi_i}; 5*64*64*2
#define W1T_OFF  40960                   // W1T[j][r]  (64 x 128)
#define W2T_OFF  (40960 + 8192)          // W2T[j][r]  (128 x 64)
#define W3T_OFF  (40960 + 16384)         // W3T[j][r]  (64 x 12)

// ---------------------------------------------------------------------------
// Kernel 1: build the 5 unitaries. One block per layer, 64 threads (thread =
// column c of U, held entirely in registers; the 2016-step scan is fully
// unrolled so all register indices are compile-time constants).
// ---------------------------------------------------------------------------
__global__ __launch_bounds__(64) void build_unitaries(
    const float* __restrict__ mzi, const float* __restrict__ oph,
    float* __restrict__ ws)
{
    const int l = blockIdx.x;
    const int c = threadIdx.x;

    __shared__ float cs[NMZI][4];   // {cos(phi), sin(phi), C*cos(th), C*sin(th)}
    __shared__ float ocs[NN][2];    // {cos(psi), sin(psi)}

    for (int m = c; m < NMZI; m += 64) {
        float th = mzi[l * 2 * NMZI + 2 * m];
        float ph = mzi[l * 2 * NMZI + 2 * m + 1];
        float sth, cth, sph, cph;
        sincosf(th, &sth, &cth);
        sincosf(ph, &sph, &cph);
        cs[m][0] = cph; cs[m][1] = sph;
        cs[m][2] = C_HALF * cth; cs[m][3] = C_HALF * sth;
    }
    {
        float ps = oph[l * NN + c];
        float sp, cp; sincosf(ps, &sp, &cp);
        ocs[c][0] = cp; ocs[c][1] = sp;
    }
    __syncthreads();

    float ur[NN], ui[NN];
    #pragma unroll
    for (int r = 0; r < NN; ++r) { ur[r] = (r == c) ? 1.f : 0.f; ui[r] = 0.f; }

    int m = 0;
    #pragma unroll
    for (int i = 0; i < NN - 1; ++i) {
        #pragma unroll
        for (int j = i + 1; j < NN; ++j) {
            float cph = cs[m][0], sph = cs[m][1];
            float cct = cs[m][2], cst = cs[m][3];
            // t = e^{i phi} * u_j
            float tr = cph * ur[j] - sph * ui[j];
            float ti = cph * ui[j] + sph * ur[j];
            float ar = ur[i] + tr, ai = ui[i] + ti;   // u_i + t
            float sr = ur[i] - tr, si = ui[i] - ti;   // u_i - t
            ur[i] = C_HALF * ar;            // new_i = C (u_i + t)
            ui[i] = C_HALF * ai;
            ur[j] = cct * sr - cst * si;    // new_j = C e^{i th} (u_i - t)
            ui[j] = cct * si + cst * sr;
            ++m;
        }
    }

    // store transposed with output phase folded: UC[l][c][r] = U[r][c]*e^{i psi_r}
    float* UCl = ws + UC_OFF + (l * NN + c) * NN * 2;
    #pragma unroll
    for (int r = 0; r < NN; ++r) {
        float cp = ocs[r][0], sp = ocs[r][1];
        UCl[2 * r]     = cp * ur[r] - sp * ui[r];
        UCl[2 * r + 1] = cp * ui[r] + sp * ur[r];
    }
}

// ---------------------------------------------------------------------------
// Kernel 2: transpose MLP weights into ws (read-coalesced, tiny).
// ---------------------------------------------------------------------------
__global__ void prep_weights(const float* __restrict__ W1,
                             const float* __restrict__ W2,
                             const float* __restrict__ W3,
                             float* __restrict__ ws)
{
    int idx = blockIdx.x * 256 + threadIdx.x;
    if (idx < 8192) {                       // W1 (128,64) -> W1T[j][r] (64,128)
        int r = idx >> 6, j = idx & 63;
        ws[W1T_OFF + j * 128 + r] = W1[idx];
    } else if (idx < 16384) {               // W2 (64,128) -> W2T[j][r] (128,64)
        int t = idx - 8192;
        int r = t >> 7, j = t & 127;
        ws[W2T_OFF + j * 64 + r] = W2[t];
    } else if (idx < 17152) {               // W3 (12,64) -> W3T[j][r] (64,12)
        int t = idx - 16384;
        int r = t >> 6, j = t & 63;
        ws[W3T_OFF + j * 12 + r] = W3[t];
    }
}

// ---------------------------------------------------------------------------
// Kernel 3: main. 64 samples/block, 256 threads. lane = sample, wave w owns
// output rows [16w,16w+16). Field in LDS (stride-65 SoA, conflict-free);
// U rows are wave-uniform contiguous 128B runs -> scalar loads.
// ---------------------------------------------------------------------------
__global__ __launch_bounds__(256) void ficonn_main(
    const float* __restrict__ x,
    const float* __restrict__ beta_param,
    const float* __restrict__ det0,
    const float* __restrict__ b1,
    const float* __restrict__ b2,
    const float* __restrict__ b3,
    const float* __restrict__ ws,
    float* __restrict__ out)
{
    __shared__ float sA[4160];   // field re (stride 65) / power / h2 (stride 64)
    __shared__ float sB[8192];   // field im (stride 65) / h1 (128 x 64)

    const int s = threadIdx.x & 63;
    const int w = __builtin_amdgcn_readfirstlane(threadIdx.x >> 6);
    const int base = blockIdx.x * 64;

    // load x tile: coalesced global, conflict-free LDS (stride 65)
    #pragma unroll
    for (int it = 0; it < 16; ++it) {
        int idx = threadIdx.x + it * 256;
        int j = idx & 63, ss = idx >> 6;
        sA[j * 65 + ss] = x[(base + ss) * 64 + j];
        sB[j * 65 + ss] = 0.f;
    }
    __syncthreads();

    float ar[16], ai[16];
    const float* UC = ws + UC_OFF;

    for (int l = 0; l < LL; ++l) {
        #pragma unroll
        for (int k = 0; k < 16; ++k) { ar[k] = 0.f; ai[k] = 0.f; }

        const float* Ul = UC + l * 8192 + w * 32;   // + j*128 per step
        #pragma unroll 2
        for (int j = 0; j < 64; ++j) {
            float fr = sA[j * 65 + s];
            float fi = sB[j * 65 + s];
            const float* Uj = Ul + j * 128;         // wave-uniform, contiguous
            #pragma unroll
            for (int k = 0; k < 16; ++k) {
                float cr = Uj[2 * k], ci = Uj[2 * k + 1];
                ar[k] = fmaf(cr, fr, fmaf(-ci, fi, ar[k]));
                ai[k] = fmaf(cr, fi, fmaf( ci, fr, ai[k]));
            }
        }
        __syncthreads();   // all reads of field done before overwrite

        if (l < LL - 1) {
            #pragma unroll
            for (int k = 0; k < 16; ++k) {
                int row = w * 16 + k;
                float bp = beta_param[l * 64 + row];
                float beta = 1.f / (1.f + expf(-bp));
                float p = ar[k] * ar[k] + ai[k] * ai[k];
                float det = det0[l * 64 + row] + SENSRESP * beta * p;
                float den = GAMMA_ * GAMMA_ + det * det;
                float sc = sqrtf(fmaxf(1.f - beta, 0.f)) * GAMMA_ / den;
                float nr = sc * (GAMMA_ * ar[k] + det * ai[k]);
                float ni = sc * (GAMMA_ * ai[k] - det * ar[k]);
                sA[row * 65 + s] = nr;
                sB[row * 65 + s] = ni;
            }
        } else {
            #pragma unroll
            for (int k = 0; k < 16; ++k) {
                int row = w * 16 + k;
                sA[row * 65 + s] = ar[k] * ar[k] + ai[k] * ai[k];  // power
            }
        }
        __syncthreads();
    }

    // ---- MLP ----
    // h1 = relu(W1 @ power + b1): wave w -> rows [32w, 32w+32)
    {
        float h[32];
        #pragma unroll
        for (int k = 0; k < 32; ++k) h[k] = 0.f;
        const float* W1T = ws + W1T_OFF + w * 32;
        #pragma unroll 2
        for (int j = 0; j < 64; ++j) {
            float f = sA[j * 65 + s];
            const float* r_ = W1T + j * 128;
            #pragma unroll
            for (int k = 0; k < 32; ++k) h[k] = fmaf(r_[k], f, h[k]);
        }
        // sB(im) is dead (post-layer-4 barrier passed); write h1 there
        #pragma unroll
        for (int k = 0; k < 32; ++k)
            sB[(w * 32 + k) * 64 + s] = fmaxf(h[k] + b1[w * 32 + k], 0.f);
        __syncthreads();
    }

    // h2 = relu(W2 @ h1 + b2): wave w -> rows [16w, 16w+16)
    {
        float g[16];
        #pragma unroll
        for (int k = 0; k < 16; ++k) g[k] = 0.f;
        const float* W2T = ws + W2T_OFF + w * 16;
        #pragma unroll 2
        for (int j = 0; j < 128; ++j) {
            float f = sB[j * 64 + s];
            const float* r_ = W2T + j * 64;
            #pragma unroll
            for (int k = 0; k < 16; ++k) g[k] = fmaf(r_[k], f, g[k]);
        }
        // sA(power) is dead (all waves past W1 loop via the h1 barrier)
        #pragma unroll
        for (int k = 0; k < 16; ++k)
            sA[(w * 16 + k) * 64 + s] = fmaxf(g[k] + b2[w * 16 + k], 0.f);
        __syncthreads();
    }

    // out = W3 @ h2 + b3: wave w -> rows [3w, 3w+3)
    {
        float o0 = 0.f, o1 = 0.f, o2 = 0.f;
        const float* W3T = ws + W3T_OFF + w * 3;
        #pragma unroll 4
        for (int j = 0; j < 64; ++j) {
            float f = sA[j * 64 + s];
            const float* r_ = W3T + j * 12;
            o0 = fmaf(r_[0], f, o0);
            o1 = fmaf(r_[1], f, o1);
            o2 = fmaf(r_[2], f, o2);
        }
        float* op = out + (size_t)(base + s) * 12 + w * 3;
        op[0] = o0 + b3[w * 3 + 0];
        op[1] = o1 + b3[w * 3 + 1];
        op[2] = o2 + b3[w * 3 + 2];
    }
}

extern "C" void kernel_launch(void* const* d_in, const int* in_sizes, int n_in,
                              void* d_out, int out_size, void* d_ws, size_t ws_size,
                              hipStream_t stream)
{
    const float* x    = (const float*)d_in[0];
    const float* mzi  = (const float*)d_in[1];
    const float* oph  = (const float*)d_in[2];
    const float* beta = (const float*)d_in[3];
    const float* det0 = (const float*)d_in[4];
    const float* W1   = (const float*)d_in[5];
    const float* b1   = (const float*)d_in[6];
    const float* W2   = (const float*)d_in[7];
    const float* b2   = (const float*)d_in[8];
    const float* W3   = (const float*)d_in[9];
    const float* b3   = (const float*)d_in[10];
    float* ws  = (float*)d_ws;
    float* out = (float*)d_out;

    const int B = in_sizes[0] / NN;       // 262144
    const int blocks = B / 64;            // 4096

    hipLaunchKernelGGL(build_unitaries, dim3(LL), dim3(64), 0, stream, mzi, oph, ws);
    hipLaunchKernelGGL(prep_weights, dim3(67), dim3(256), 0, stream, W1, W2, W3, ws);
    hipLaunchKernelGGL(ficonn_main, dim3(blocks), dim3(256), 0, stream,
                       x, beta, det0, b1, b2, b3, ws, out);
}